// Round 2
// baseline (2764.676 us; speedup 1.0000x reference)
//
#include <hip/hip_runtime.h>

#define FD 128          // feature dim
#define NCH 8           // feature chunks == XCD count
#define CF 16           // features per chunk (FD / NCH)
#define RPB 16          // rows per block (256 threads / 16 lanes-per-row)

// ---------------- CSR build ----------------

__global__ void zero_i32(int* __restrict__ p, int n) {
  int i = blockIdx.x * blockDim.x + threadIdx.x;
  if (i < n) p[i] = 0;
}

__global__ void hist_kernel(const int* __restrict__ rows, int* __restrict__ cnt, int nnz) {
  int i = blockIdx.x * blockDim.x + threadIdx.x;
  if (i < nnz) atomicAdd(&cnt[rows[i]], 1);
}

// single-block scan, thread-serial partials: row_ptr[0]=0, row_ptr[i+1]=sum(cnt[0..i])
__global__ void scan_kernel(const int* __restrict__ cnt, int* __restrict__ row_ptr, int n) {
  __shared__ int sm[1024];
  const int tid = threadIdx.x;
  const int chunk = (n + 1023) >> 10;
  const int lo = tid * chunk;
  const int hi = min(lo + chunk, n);
  int s = 0;
  for (int i = lo; i < hi; ++i) s += cnt[i];
  sm[tid] = s;
  __syncthreads();
  for (int off = 1; off < 1024; off <<= 1) {
    int t = (tid >= off) ? sm[tid - off] : 0;
    __syncthreads();
    sm[tid] += t;
    __syncthreads();
  }
  int pre = (tid == 0) ? 0 : sm[tid - 1];
  for (int i = lo; i < hi; ++i) { pre += cnt[i]; row_ptr[i + 1] = pre; }
  if (tid == 0) row_ptr[0] = 0;
}

__global__ void copy_i32(const int* __restrict__ src, int* __restrict__ dst, int n) {
  int i = blockIdx.x * blockDim.x + threadIdx.x;
  if (i < n) dst[i] = src[i];
}

__global__ void scatter_kernel(const int* __restrict__ rows, const int* __restrict__ cols,
                               const float* __restrict__ vals, int* __restrict__ fill,
                               int* __restrict__ cols_s, float* __restrict__ vals_s, int nnz) {
  int i = blockIdx.x * blockDim.x + threadIdx.x;
  if (i < nnz) {
    int r = rows[i];
    int pos = atomicAdd(&fill[r], 1);
    cols_s[pos] = cols[i];
    vals_s[pos] = vals[i];
  }
}

// ---------------- chunked SpMM ----------------
// chunk = blockIdx.x % 8 -> rides the round-robin block->XCD mapping, so each
// XCD's gathers touch only its own 3.2 MB [chunk][n][16] buffer (fits 4 MB L2).
// 16 lanes per row x 16 features = 64B coalesced gather per edge.

__device__ __forceinline__ float gather16(const int* __restrict__ rp,
                                          const int* __restrict__ cols,
                                          const float* __restrict__ vals,
                                          const float* __restrict__ src,  // base of this chunk
                                          size_t stride,                  // 16 (chunked) or 128 (X)
                                          int r, int f) {
  int e = rp[r];
  const int end = rp[r + 1];
  float a0 = 0.f, a1 = 0.f;
  for (; e + 3 < end; e += 4) {
    int c0 = cols[e + 0], c1 = cols[e + 1], c2 = cols[e + 2], c3 = cols[e + 3];
    float v0 = vals[e + 0], v1 = vals[e + 1], v2 = vals[e + 2], v3 = vals[e + 3];
    float x0 = src[(size_t)c0 * stride + f];
    float x1 = src[(size_t)c1 * stride + f];
    float x2 = src[(size_t)c2 * stride + f];
    float x3 = src[(size_t)c3 * stride + f];
    a0 = fmaf(v0, x0, a0);
    a1 = fmaf(v1, x1, a1);
    a0 = fmaf(v2, x2, a0);
    a1 = fmaf(v3, x3, a1);
  }
  for (; e < end; ++e)
    a0 = fmaf(vals[e], src[(size_t)cols[e] * stride + f], a0);
  return a0 + a1;
}

// k=1: T1 = L@X (gather from strided X); out = c0*X + c1*T1
__global__ __launch_bounds__(256) void spmm_first_ck(
    const int* __restrict__ rp, const int* __restrict__ cols, const float* __restrict__ vals,
    const float* __restrict__ X, float* __restrict__ T1, float* __restrict__ out,
    const float* __restrict__ coeffs, int n) {
  const int t = threadIdx.x, f = t & (CF - 1), g = t >> 4;
  const int chunk = blockIdx.x & (NCH - 1);
  const int r = (int)(blockIdx.x >> 3) * RPB + g;
  if (r >= n) return;
  const int foff = chunk * CF;
  float sum = gather16(rp, cols, vals, X + foff, FD, r, f);
  T1[((size_t)chunk * n + r) * CF + f] = sum;
  float x0 = X[(size_t)r * FD + foff + f];
  out[(size_t)r * FD + foff + f] = fmaf(coeffs[1], sum, coeffs[0] * x0);
}

// k>=2: Tk = 2*(L@src) - prev ; out += ck*Tk ; Tk -> dst (chunked).
// prev_strided==1 -> prev is X in [n][128] layout (k==2); else prev==dst (in-place).
__global__ __launch_bounds__(256) void spmm_step_ck(
    const int* __restrict__ rp, const int* __restrict__ cols, const float* __restrict__ vals,
    const float* __restrict__ src, const float* prev, float* dst, float* __restrict__ out,
    const float* __restrict__ coeffs, int k, int n, int prev_strided) {
  const int t = threadIdx.x, f = t & (CF - 1), g = t >> 4;
  const int chunk = blockIdx.x & (NCH - 1);
  const int r = (int)(blockIdx.x >> 3) * RPB + g;
  if (r >= n) return;
  const float* sc = src + (size_t)chunk * n * CF;
  float sum = gather16(rp, cols, vals, sc, CF, r, f);
  const float ck = coeffs[k];
  const size_t ci = ((size_t)chunk * n + r) * CF + f;
  const size_t oi = (size_t)r * FD + chunk * CF + f;
  float p = prev_strided ? prev[oi - (size_t)0 + 0] * 0.f + prev[(size_t)r * FD + chunk * CF + f]
                         : dst[ci];
  // (prev_strided: prev==X at strided index; else in-place read of dst)
  float tk = fmaf(2.f, sum, -p);
  dst[ci] = tk;
  out[oi] = fmaf(ck, tk, out[oi]);
}

// ---------------- launch ----------------

extern "C" void kernel_launch(void* const* d_in, const int* in_sizes, int n_in,
                              void* d_out, int out_size, void* d_ws, size_t ws_size,
                              hipStream_t stream) {
  const int* rows = (const int*)d_in[0];
  const int* cols = (const int*)d_in[1];
  const float* vals = (const float*)d_in[2];
  const float* X = (const float*)d_in[3];
  const float* coeffs = (const float*)d_in[4];
  float* out = (float*)d_out;

  const int nnz = in_sizes[0];
  const int n = in_sizes[3] / FD;
  const int M = in_sizes[4];

  auto align_up = [](size_t x) { return (x + 255) & ~(size_t)255; };
  char* w = (char*)d_ws;
  size_t off = 0;
  int* row_ptr = (int*)(w + off); off = align_up(off + (size_t)(n + 1) * 4);
  int* row_fill = (int*)(w + off); off = align_up(off + (size_t)n * 4);
  int* cols_s = (int*)(w + off); off = align_up(off + (size_t)nnz * 4);
  float* vals_s = (float*)(w + off); off = align_up(off + (size_t)nnz * 4);
  float* buf0 = (float*)(w + off); off = align_up(off + (size_t)n * FD * 4);
  float* buf1 = (float*)(w + off); off = align_up(off + (size_t)n * FD * 4);
  (void)ws_size;

  const int B = 256;
  const int gN = (n + B - 1) / B;
  const int gE = (nnz + B - 1) / B;
  const int gS = NCH * ((n + RPB - 1) / RPB);

  // CSR build (workspace is re-poisoned before every call)
  zero_i32<<<gN, B, 0, stream>>>(row_fill, n);
  hist_kernel<<<gE, B, 0, stream>>>(rows, row_fill, nnz);
  scan_kernel<<<1, 1024, 0, stream>>>(row_fill, row_ptr, n);
  copy_i32<<<gN, B, 0, stream>>>(row_ptr, row_fill, n);
  scatter_kernel<<<gE, B, 0, stream>>>(rows, cols, vals, row_fill, cols_s, vals_s, nnz);

  // k = 1: T1 -> buf0
  spmm_first_ck<<<gS, B, 0, stream>>>(row_ptr, cols_s, vals_s, X, buf0, out, coeffs, n);
  // k = 2: src = buf0 (T1), prev = X (strided), dst = buf1 (T2)
  if (M > 2)
    spmm_step_ck<<<gS, B, 0, stream>>>(row_ptr, cols_s, vals_s, buf0, X, buf1, out,
                                       coeffs, 2, n, 1);
  // k >= 3: src = bufs[k&1], prev = dst = other (in-place)
  for (int k = 3; k < M; ++k) {
    float* src = (k & 1) ? buf1 : buf0;
    float* pd  = (k & 1) ? buf0 : buf1;
    spmm_step_ck<<<gS, B, 0, stream>>>(row_ptr, cols_s, vals_s, src, pd, pd, out,
                                       coeffs, k, n, 0);
  }
}

// Round 3
// 1619.189 us; speedup vs baseline: 1.7074x; 1.7074x over previous
//
#include <hip/hip_runtime.h>
#include <hip/hip_fp16.h>

#define FD 128          // feature dim
#define RPB 4           // rows (waves) per block; block = 256 threads

// ---------------- CSR build ----------------

__global__ void zero_i32(int* __restrict__ p, int n) {
  int i = blockIdx.x * blockDim.x + threadIdx.x;
  if (i < n) p[i] = 0;
}

__global__ void hist_kernel(const int* __restrict__ rows, int* __restrict__ cnt, int nnz) {
  int i = blockIdx.x * blockDim.x + threadIdx.x;
  if (i < nnz) atomicAdd(&cnt[rows[i]], 1);
}

// single-block scan, thread-serial partials (fast version from R2: ~6 us)
__global__ void scan_kernel(const int* __restrict__ cnt, int* __restrict__ row_ptr, int n) {
  __shared__ int sm[1024];
  const int tid = threadIdx.x;
  const int chunk = (n + 1023) >> 10;
  const int lo = min(tid * chunk, n);
  const int hi = min(lo + chunk, n);
  int s = 0;
  for (int i = lo; i < hi; ++i) s += cnt[i];
  sm[tid] = s;
  __syncthreads();
  for (int off = 1; off < 1024; off <<= 1) {
    int t = (tid >= off) ? sm[tid - off] : 0;
    __syncthreads();
    sm[tid] += t;
    __syncthreads();
  }
  int pre = (tid == 0) ? 0 : sm[tid - 1];
  for (int i = lo; i < hi; ++i) { pre += cnt[i]; row_ptr[i + 1] = pre; }
  if (tid == 0) row_ptr[0] = 0;
}

__global__ void copy_i32(const int* __restrict__ src, int* __restrict__ dst, int n) {
  int i = blockIdx.x * blockDim.x + threadIdx.x;
  if (i < n) dst[i] = src[i];
}

__global__ void scatter_kernel(const int* __restrict__ rows, const int* __restrict__ cols,
                               const float* __restrict__ vals, int* __restrict__ fill,
                               int* __restrict__ cols_s, float* __restrict__ vals_s, int nnz) {
  int i = blockIdx.x * blockDim.x + threadIdx.x;
  if (i < nnz) {
    int r = rows[i];
    int pos = atomicAdd(&fill[r], 1);
    cols_s[pos] = cols[i];
    vals_s[pos] = vals[i];
  }
}

// X (f32, [n][128]) -> Xh (f16, [n][128]); 4 elems/thread
__global__ void f32_to_f16(const float* __restrict__ src, __half* __restrict__ dst, int n4) {
  int i = blockIdx.x * blockDim.x + threadIdx.x;
  if (i < n4) {
    float4 v = ((const float4*)src)[i];
    __half2* d = (__half2*)dst + 2 * (size_t)i;
    d[0] = __floats2half2_rn(v.x, v.y);
    d[1] = __floats2half2_rn(v.z, v.w);
  }
}

// ---------------- SpMM (fp16 gather source, fp32 math) ----------------
// One wave (64 lanes) per row; lane owns a __half2 (2 features) -> 128 features.
// Gather of T[c,:] is one coalesced 256B sweep per edge. cols/vals loads are
// wave-uniform -> scalar broadcast.

__device__ __forceinline__ float2 gather_h(const int* __restrict__ rp,
                                           const int* __restrict__ cols,
                                           const float* __restrict__ vals,
                                           const __half* __restrict__ T,
                                           int r, int lane) {
  int e = rp[r];
  const int end = rp[r + 1];
  float2 s0 = make_float2(0.f, 0.f);
  float2 s1 = make_float2(0.f, 0.f);
  for (; e + 3 < end; e += 4) {
    int c0 = cols[e + 0], c1 = cols[e + 1], c2 = cols[e + 2], c3 = cols[e + 3];
    float v0 = vals[e + 0], v1 = vals[e + 1], v2 = vals[e + 2], v3 = vals[e + 3];
    float2 x0 = __half22float2(((const __half2*)(T + (size_t)c0 * FD))[lane]);
    float2 x1 = __half22float2(((const __half2*)(T + (size_t)c1 * FD))[lane]);
    float2 x2 = __half22float2(((const __half2*)(T + (size_t)c2 * FD))[lane]);
    float2 x3 = __half22float2(((const __half2*)(T + (size_t)c3 * FD))[lane]);
    s0.x = fmaf(v0, x0.x, s0.x); s0.y = fmaf(v0, x0.y, s0.y);
    s1.x = fmaf(v1, x1.x, s1.x); s1.y = fmaf(v1, x1.y, s1.y);
    s0.x = fmaf(v2, x2.x, s0.x); s0.y = fmaf(v2, x2.y, s0.y);
    s1.x = fmaf(v3, x3.x, s1.x); s1.y = fmaf(v3, x3.y, s1.y);
  }
  for (; e < end; ++e) {
    float v = vals[e];
    float2 x = __half22float2(((const __half2*)(T + (size_t)cols[e] * FD))[lane]);
    s0.x = fmaf(v, x.x, s0.x); s0.y = fmaf(v, x.y, s0.y);
  }
  return make_float2(s0.x + s1.x, s0.y + s1.y);
}

// k=1: T1 = L@X (gather fp16 Xh); acc = c0*X + c1*T1 (fp32 X for the epilogue)
__global__ __launch_bounds__(256) void spmm_first(
    const int* __restrict__ rp, const int* __restrict__ cols, const float* __restrict__ vals,
    const __half* __restrict__ Xh, const float* __restrict__ X,
    __half* __restrict__ T1, float* __restrict__ out,
    const float* __restrict__ coeffs, int n) {
  const int lane = threadIdx.x & 63;
  const int r = blockIdx.x * RPB + (threadIdx.x >> 6);
  if (r >= n) return;
  float2 sum = gather_h(rp, cols, vals, Xh, r, lane);
  ((__half2*)(T1 + (size_t)r * FD))[lane] = __floats2half2_rn(sum.x, sum.y);
  const float c0 = coeffs[0], c1 = coeffs[1];
  float2 x = ((const float2*)(X + (size_t)r * FD))[lane];
  float2 a;
  a.x = fmaf(c1, sum.x, c0 * x.x);
  a.y = fmaf(c1, sum.y, c0 * x.y);
  ((float2*)(out + (size_t)r * FD))[lane] = a;
}

// k>=2: Tk = 2*(L@src) - prev ; out += ck*Tk ; Tk -> dst (all T buffers fp16).
// prev may alias dst (same element read-then-written by the same thread).
__global__ __launch_bounds__(256) void spmm_step(
    const int* __restrict__ rp, const int* __restrict__ cols, const float* __restrict__ vals,
    const __half* __restrict__ src, const __half* prev, __half* dst,
    float* __restrict__ out, const float* __restrict__ coeffs, int k, int n) {
  const int lane = threadIdx.x & 63;
  const int r = blockIdx.x * RPB + (threadIdx.x >> 6);
  if (r >= n) return;
  float2 sum = gather_h(rp, cols, vals, src, r, lane);
  const float ck = coeffs[k];
  float2 p = __half22float2(((const __half2*)(prev + (size_t)r * FD))[lane]);
  float2 t;
  t.x = fmaf(2.f, sum.x, -p.x);
  t.y = fmaf(2.f, sum.y, -p.y);
  ((__half2*)(dst + (size_t)r * FD))[lane] = __floats2half2_rn(t.x, t.y);
  float2 a = ((float2*)(out + (size_t)r * FD))[lane];
  a.x = fmaf(ck, t.x, a.x);
  a.y = fmaf(ck, t.y, a.y);
  ((float2*)(out + (size_t)r * FD))[lane] = a;
}

// ---------------- launch ----------------

extern "C" void kernel_launch(void* const* d_in, const int* in_sizes, int n_in,
                              void* d_out, int out_size, void* d_ws, size_t ws_size,
                              hipStream_t stream) {
  const int* rows = (const int*)d_in[0];
  const int* cols = (const int*)d_in[1];
  const float* vals = (const float*)d_in[2];
  const float* X = (const float*)d_in[3];
  const float* coeffs = (const float*)d_in[4];
  float* out = (float*)d_out;

  const int nnz = in_sizes[0];
  const int n = in_sizes[3] / FD;
  const int M = in_sizes[4];

  auto align_up = [](size_t x) { return (x + 255) & ~(size_t)255; };
  char* w = (char*)d_ws;
  size_t off = 0;
  int* row_ptr = (int*)(w + off); off = align_up(off + (size_t)(n + 1) * 4);
  int* row_fill = (int*)(w + off); off = align_up(off + (size_t)n * 4);
  int* cols_s = (int*)(w + off); off = align_up(off + (size_t)nnz * 4);
  float* vals_s = (float*)(w + off); off = align_up(off + (size_t)nnz * 4);
  __half* Xh = (__half*)(w + off); off = align_up(off + (size_t)n * FD * 2);
  __half* buf0 = (__half*)(w + off); off = align_up(off + (size_t)n * FD * 2);
  __half* buf1 = (__half*)(w + off); off = align_up(off + (size_t)n * FD * 2);
  (void)ws_size;

  const int B = 256;
  const int gN = (n + B - 1) / B;
  const int gE = (nnz + B - 1) / B;
  const int gS = (n + RPB - 1) / RPB;
  const int n4 = n * FD / 4;
  const int gC = (n4 + B - 1) / B;

  // CSR build (workspace is re-poisoned before every call)
  zero_i32<<<gN, B, 0, stream>>>(row_fill, n);
  hist_kernel<<<gE, B, 0, stream>>>(rows, row_fill, nnz);
  scan_kernel<<<1, 1024, 0, stream>>>(row_fill, row_ptr, n);
  copy_i32<<<gN, B, 0, stream>>>(row_ptr, row_fill, n);
  scatter_kernel<<<gE, B, 0, stream>>>(rows, cols, vals, row_fill, cols_s, vals_s, nnz);
  f32_to_f16<<<gC, B, 0, stream>>>(X, Xh, n4);

  // k = 1: T1 -> buf0
  spmm_first<<<gS, B, 0, stream>>>(row_ptr, cols_s, vals_s, Xh, X, buf0, out, coeffs, n);
  // k = 2: src = buf0 (T1), prev = Xh, dst = buf1 (T2)
  if (M > 2)
    spmm_step<<<gS, B, 0, stream>>>(row_ptr, cols_s, vals_s, buf0, Xh, buf1, out,
                                    coeffs, 2, n);
  // k >= 3: src = bufs[k&1], prev = dst = other (in-place)
  for (int k = 3; k < M; ++k) {
    __half* src = (k & 1) ? buf1 : buf0;
    __half* pd  = (k & 1) ? buf0 : buf1;
    spmm_step<<<gS, B, 0, stream>>>(row_ptr, cols_s, vals_s, src, pd, pd, out,
                                    coeffs, k, n);
  }
}